// Round 15
// baseline (268.452 us; speedup 1.0000x reference)
//
#include <hip/hip_runtime.h>
#include <hip/hip_bf16.h>

typedef _Float16 f16;
typedef _Float16 half8 __attribute__((ext_vector_type(8)));
typedef _Float16 half4 __attribute__((ext_vector_type(4)));
typedef float f32x4 __attribute__((ext_vector_type(4)));

typedef const __attribute__((address_space(1))) void gvoid;
typedef __attribute__((address_space(3))) void lvoid;
#define GLOAD16(src, dst) __builtin_amdgcn_global_load_lds((gvoid*)(src), (lvoid*)(dst), 16, 0, 0)

// ---------------- workspace layout (bytes) ----------------
#define WQV_OFF   0u          // f32 [256][256]  Wq*Vp
#define WKT_OFF   262144u     // f32 [256][256]  Wk*Tp
#define KP_OFF    524288u     // f32 [512][256]  fused k-projection (l*16+b rows)
#define W2S_OFF   1048576u    // row-image W2s: [16 b][4 kc][256 j][128B] (swizzle baked)
#define SBIAS_OFF 3145728u    // f32 [16][256]
#define BQV_OFF   3162112u    // f32 [256]
#define BKT_OFF   3163136u    // f32 [256]
#define W1H_OFF   3164160u    // row-image W1: [4 kc][256 o][128B]
#define W2H_OFF   3295232u    // frag-major W2: [8 ot][4 kc][2 mi][64 lane][16B] (64 KB)
#define VARP_OFF  3360768u    // f32 [16][256]
#define SMM_OFF   3377280u    // u32 [16][2]
#define FMM_OFF   3377408u    // u32 [16][2]
#define CAND_OFF  3377664u    // f32 [9][16][16384]  plane-major candidates
#define FI_OFF    12814848u   // f32 [16][16384]
#define SIM_OFF   13863424u   // f32 [16][16384]

__device__ __forceinline__ float sigm(float x) { return 1.f / (1.f + __expf(-x)); }
__device__ __forceinline__ unsigned fmap(float f) {
  unsigned u = __float_as_uint(f);
  return (u & 0x80000000u) ? ~u : (u | 0x80000000u);
}
__device__ __forceinline__ float funmap(unsigned u) {
  unsigned b = (u & 0x80000000u) ? (u & 0x7FFFFFFFu) : ~u;
  return __uint_as_float(b);
}
// frag-major byte offset for element (row o, col c) of a [O][256] f16 matrix
__device__ __forceinline__ unsigned fragoff(int o, int c) {
  int ot = o >> 4, ln = o & 15;
  int kc = c >> 6, mi = (c >> 5) & 1, kg = (c >> 3) & 3, h8 = c & 7;
  return (unsigned)((((ot * 4 + kc) * 2 + mi) << 10) + ((kg * 16 + ln) << 4) + h8 * 2);
}

// ---------------- P1: Wqv = Wq*Vp, Wkt = Wk*Tp, fused biases (+minmax init) --------
__global__ void k_p1(const float* __restrict__ ipw, const float* __restrict__ ipb,
                     const float* __restrict__ vp_w, const float* __restrict__ vp_b,
                     const float* __restrict__ tp_w, const float* __restrict__ tp_b,
                     float* __restrict__ Wqv, float* __restrict__ Wkt,
                     float* __restrict__ bqv, float* __restrict__ bkt,
                     unsigned* __restrict__ simMM, unsigned* __restrict__ fiMM) {
  int tx = threadIdx.x, ty = threadIdx.y;
  int bz = blockIdx.z;
  if (bz == 2) {
    if (blockIdx.x || blockIdx.y) return;
    if (ty == 0 && tx < 16) {
      simMM[tx * 2] = 0xFFFFFFFFu; simMM[tx * 2 + 1] = 0u;
      fiMM[tx * 2] = 0xFFFFFFFFu;  fiMM[tx * 2 + 1] = 0u;
    }
    int j = ty * 16 + tx;
    float s1 = 0.f, s2 = 0.f;
    for (int k = 0; k < 256; ++k) {
      s1 += ipw[j * 256 + k] * vp_b[k];
      s2 += ipw[65536 + j * 256 + k] * tp_b[k];
    }
    bqv[j] = s1 + ipb[j];
    bkt[j] = s2 + ipb[256 + j];
    return;
  }
  const float* A = ipw + (bz ? 65536 : 0);
  const float* B = bz ? tp_w : vp_w;
  float* O = bz ? Wkt : Wqv;
  __shared__ float As[16][16], Bs[16][17];
  int row = blockIdx.y * 16 + ty, col = blockIdx.x * 16 + tx;
  float s = 0.f;
  for (int tt = 0; tt < 16; ++tt) {
    As[ty][tx] = A[row * 256 + tt * 16 + tx];
    Bs[ty][tx] = B[(tt * 16 + ty) * 256 + col];
    __syncthreads();
#pragma unroll
    for (int k = 0; k < 16; ++k) s += As[ty][k] * Bs[k][tx];
    __syncthreads();
  }
  O[row * 256 + col] = s;
}

// ---------------- convert: W1 -> row-image, W2 -> frag-major ----------------
__global__ void k_conv(const float* __restrict__ w1, const float* __restrict__ w2,
                       char* __restrict__ W1g, char* __restrict__ W2g) {
  int i = blockIdx.x * 256 + threadIdx.x;
  if (i < 65536) {
    int o = i >> 8, c = i & 255;
    *(f16*)(W1g + (c >> 6) * 32768 + o * 128 + (((c & 63) << 1) ^ ((o & 7) << 4))) = (f16)w1[i];
  } else if (i < 98304) {
    int i2 = i - 65536;
    int o = i2 >> 8, c = i2 & 255;
    *(f16*)(W2g + fragoff(o, c)) = (f16)w2[i2];
  }
}

// ---------------- P2: kp[lb][i] = T[lb]·Wkt[i] + bkt[i] ----------------
__global__ void k_p2(const float* __restrict__ T, const float* __restrict__ Wkt,
                     const float* __restrict__ bkt, float* __restrict__ kp) {
  __shared__ float As[16][16], Ws[16][17];
  int tx = threadIdx.x, ty = threadIdx.y;
  int lb = blockIdx.y * 16 + ty;
  int i = blockIdx.x * 16 + tx;
  float s = 0.f;
  for (int tt = 0; tt < 16; ++tt) {
    As[ty][tx] = T[(size_t)lb * 256 + tt * 16 + tx];
    Ws[ty][tx] = Wkt[(size_t)(blockIdx.x * 16 + ty) * 256 + tt * 16 + tx];
    __syncthreads();
#pragma unroll
    for (int k = 0; k < 16; ++k) s += As[ty][k] * Ws[tx][k];
    __syncthreads();
  }
  kp[(size_t)lb * 256 + i] = s + bkt[i];
}

// ---------------- P3: W2s (pre-swizzled row-image) + sbias ----------------
__global__ void k_p3(const float* __restrict__ kp, const float* __restrict__ Wqv,
                     const float* __restrict__ bqv, char* __restrict__ W2sg,
                     float* __restrict__ sbias) {
  const float SC = 0.17677669529663687f; // 1/sqrt(32)
  int b = blockIdx.z, jt = blockIdx.y, ct = blockIdx.x;
  int ty = threadIdx.y, tx = threadIdx.x;
  int j2 = jt * 16 + ty, c = ct * 16 + tx;
  int h = j2 >> 5, l = j2 & 31;
  const float* kr = kp + (size_t)(l * 16 + b) * 256 + h * 32;
  const float* wq = Wqv + (size_t)h * 32 * 256 + c;
  float s = 0.f;
#pragma unroll
  for (int d = 0; d < 32; ++d) s += kr[d] * wq[(size_t)d * 256];
  *(f16*)(W2sg + (size_t)b * 131072 + (c >> 6) * 32768 + j2 * 128 +
          (((c & 63) << 1) ^ ((j2 & 7) << 4))) = (f16)(s * SC);
  if (ct == 0 && tx == 0) {
    float sb = 0.f;
#pragma unroll
    for (int d = 0; d < 32; ++d) sb += kr[d] * bqv[h * 32 + d];
    sbias[b * 256 + j2] = sb * SC;
  }
}

// ============ k_main: grid (512,16). z = bx&1 (0 scores, 1 MLP), tile = bx>>1. ============
// Twin blocks (same tile, both z) are dispatch-adjacent -> co-resident, same XCD ->
// the MLP twin's X reads hit L2. LDS 40960 -> 4 blocks/CU.
__global__ void __launch_bounds__(256, 4) k_main(
    const float* __restrict__ X, const char* __restrict__ W2sg,
    const float* __restrict__ sbias,
    const char* __restrict__ W1g, const char* __restrict__ W2g,
    const float* __restrict__ b1, const float* __restrict__ g1, const float* __restrict__ be1,
    const float* __restrict__ b2, const float* __restrict__ g2, const float* __restrict__ be2,
    const float* __restrict__ w3, const float* __restrict__ b3,
    float* __restrict__ cand, float* __restrict__ varpart, float* __restrict__ fi) {
  __shared__ __align__(16) char smem[40960];
  const int b = blockIdx.y;
  const int bx = blockIdx.x >> 1;     // tile index
  const int zz = blockIdx.x & 1;      // 0 = scores, 1 = MLP
  const int n0 = bx * 64;
  const int t = threadIdx.x;
  const int w = t >> 6;
  const int lane = t & 63;
  const int ln = lane & 15, kg = lane >> 4;
  char* AT = smem;
  char* BT = smem + 8192;

  auto issueA = [&](int kt) {
    int row = t >> 2, cq = t & 3;
    const float* Xr = X + ((size_t)(n0 + row) * 16 + b) * 256 + kt * 64 + cq * 16;
    f32x4 a0 = *(const f32x4*)(Xr), a1 = *(const f32x4*)(Xr + 4);
    f32x4 a2 = *(const f32x4*)(Xr + 8), a3 = *(const f32x4*)(Xr + 12);
    half8 h0, h1;
#pragma unroll
    for (int i = 0; i < 4; ++i) {
      h0[i] = (f16)a0[i]; h0[4 + i] = (f16)a1[i];
      h1[i] = (f16)a2[i]; h1[4 + i] = (f16)a3[i];
    }
    unsigned sw = (unsigned)((row & 7) << 4);
    *(half8*)(AT + ((unsigned)(row * 128 + cq * 32) ^ sw)) = h0;
    *(half8*)(AT + ((unsigned)(row * 128 + cq * 32 + 16) ^ sw)) = h1;
  };

  if (zz == 0) {
    // ================= scores path =================
    const char* Wb = W2sg + (size_t)b * 131072;
    auto issueB = [&](int kt) {
      const char* src = Wb + kt * 32768 + w * 8192 + (lane << 4);
      char* dst = BT + w * 8192;
#pragma unroll
      for (int i = 0; i < 8; ++i) GLOAD16(src + i * 1024, dst + i * 1024);
    };

    f32x4 acc[4][4];
#pragma unroll
    for (int q = 0; q < 4; ++q)
#pragma unroll
      for (int ni = 0; ni < 4; ++ni)
#pragma unroll
        for (int i = 0; i < 4; ++i) acc[q][ni][i] = 0.f;

    issueA(0); issueB(0);
    __syncthreads();
#pragma unroll
    for (int kt = 0; kt < 4; ++kt) {
      half8 av[4][2], bv[4][2];
#pragma unroll
      for (int q = 0; q < 4; ++q) {
        int o = w * 64 + q * 16 + ln;
        unsigned sw = (unsigned)((o & 7) << 4);
#pragma unroll
        for (int mi = 0; mi < 2; ++mi)
          av[q][mi] = *(const half8*)(BT + o * 128 + ((unsigned)(mi * 64 + kg * 16) ^ sw));
      }
#pragma unroll
      for (int ni = 0; ni < 4; ++ni) {
        int n = ni * 16 + ln;
        unsigned sw = (unsigned)((n & 7) << 4);
#pragma unroll
        for (int mi = 0; mi < 2; ++mi)
          bv[ni][mi] = *(const half8*)(AT + n * 128 + ((unsigned)(mi * 64 + kg * 16) ^ sw));
      }
#pragma unroll
      for (int mi = 0; mi < 2; ++mi)
#pragma unroll
        for (int q = 0; q < 4; ++q)
#pragma unroll
          for (int ni = 0; ni < 4; ++ni)
            acc[q][ni] = __builtin_amdgcn_mfma_f32_16x16x32_f16(av[q][mi], bv[ni][mi], acc[q][ni], 0, 0, 0);
      __syncthreads();
      if (kt < 3) { issueA(kt + 1); issueB(kt + 1); __syncthreads(); }
    }

    // per-head softmax (wave w: heads 2w, 2w+1), slice into dead BT
    {
      f32x4 sb[4];
#pragma unroll
      for (int q = 0; q < 4; ++q)
        sb[q] = *(const f32x4*)(sbias + b * 256 + (w * 4 + q) * 16 + kg * 4);
      float vm[4][2][4];
#pragma unroll
      for (int ni = 0; ni < 4; ++ni)
#pragma unroll
        for (int qq = 0; qq < 2; ++qq)
#pragma unroll
          for (int r = 0; r < 4; ++r) vm[ni][qq][r] = 0.f;
#pragma unroll
      for (int hh = 0; hh < 2; ++hh)
#pragma unroll
        for (int ni = 0; ni < 4; ++ni) {
          float x[2][4];
          float mx = -1e30f;
#pragma unroll
          for (int qq = 0; qq < 2; ++qq)
#pragma unroll
            for (int r = 0; r < 4; ++r) {
              x[qq][r] = acc[hh * 2 + qq][ni][r] + sb[hh * 2 + qq][r];
              mx = fmaxf(mx, x[qq][r]);
            }
          mx = fmaxf(mx, __shfl_xor(mx, 16, 64));
          mx = fmaxf(mx, __shfl_xor(mx, 32, 64));
          float S = 0.f;
#pragma unroll
          for (int qq = 0; qq < 2; ++qq)
#pragma unroll
            for (int r = 0; r < 4; ++r) { x[qq][r] = __expf(x[qq][r] - mx); S += x[qq][r]; }
          S += __shfl_xor(S, 16, 64);
          S += __shfl_xor(S, 32, 64);
          float inv = 0.125f / S;
#pragma unroll
          for (int qq = 0; qq < 2; ++qq)
#pragma unroll
            for (int r = 0; r < 4; ++r) vm[ni][qq][r] += x[qq][r] * inv;
        }
      float* slice = (float*)(smem + 8192) + w * 2048;  // [32 l][64 n]
#pragma unroll
      for (int ni = 0; ni < 4; ++ni)
#pragma unroll
        for (int qq = 0; qq < 2; ++qq)
#pragma unroll
          for (int r = 0; r < 4; ++r)
            slice[(qq * 16 + kg * 4 + r) * 64 + ni * 16 + ln] = vm[ni][qq][r];
    }
    __syncthreads();

    // wave 0: merge slices, variance, sort, candidates
    if (w == 0) {
      const float* sl = (const float*)(smem + 8192);
      float v[32];
#pragma unroll
      for (int l = 0; l < 32; ++l)
        v[l] = sl[l * 64 + lane] + sl[2048 + l * 64 + lane] +
               sl[4096 + l * 64 + lane] + sl[6144 + l * 64 + lane];
      float s2 = 0.f;
#pragma unroll
      for (int l = 0; l < 32; ++l) s2 += v[l] * v[l];
      float vr = (s2 - (1.f / 32.f)) * (1.f / 31.f);
#pragma unroll
      for (int m = 1; m < 64; m <<= 1) vr += __shfl_xor(vr, m, 64);
      if (lane == 0) varpart[b * 256 + bx] = vr;
#pragma unroll
      for (int k = 2; k <= 32; k <<= 1) {
#pragma unroll
        for (int j = k >> 1; j > 0; j >>= 1) {
#pragma unroll
          for (int i = 0; i < 32; ++i) {
            int l = i ^ j;
            if (l > i) {
              float a = v[i], c = v[l];
              float hi = fmaxf(a, c), lo = fminf(a, c);
              bool up = ((i & k) == 0);
              v[i] = up ? hi : lo;
              v[l] = up ? lo : hi;
            }
          }
        }
      }
      float m0 = v[0], se = 0.f, te = 0.f;
      float cn[9];
#pragma unroll
      for (int i = 0; i < 16; ++i) {
        float e = __expf(v[i] - m0);
        se += e; te += v[i] * e;
        if (i >= 7) cn[i - 7] = te / se;
      }
#pragma unroll
      for (int i = 0; i < 9; ++i)
        cand[(size_t)i * 262144 + (size_t)b * 16384 + n0 + lane] = cn[i];
    }
    return;
  }

  // ================= MLP path =================
  char* H1 = smem;
  // stats carved in dead BT tail (32768..35840): not overlapped by H1 (0..32K)
  float* pS = (float*)(smem + 32768);   // [64][5]
  float* pQ = (float*)(smem + 34048);   // [64][5]
  float* pM = (float*)(smem + 35328);   // [64]
  float* pR = (float*)(smem + 35584);   // [64]
  auto issueB1 = [&](int kt) {
    const char* src = W1g + kt * 32768 + w * 8192 + (lane << 4);
    char* dst = BT + w * 8192;
#pragma unroll
    for (int i = 0; i < 8; ++i) GLOAD16(src + i * 1024, dst + i * 1024);
  };

  // ---- MLP1 GEMM ----
  f32x4 acc[4][4];
#pragma unroll
  for (int q = 0; q < 4; ++q)
#pragma unroll
    for (int ni = 0; ni < 4; ++ni)
#pragma unroll
      for (int i = 0; i < 4; ++i) acc[q][ni][i] = 0.f;

  issueA(0); issueB1(0);
  __syncthreads();
#pragma unroll
  for (int kt = 0; kt < 4; ++kt) {
    half8 av[4][2], bv[4][2];
#pragma unroll
    for (int q = 0; q < 4; ++q) {
      int o = w * 64 + q * 16 + ln;
      unsigned sw = (unsigned)((o & 7) << 4);
#pragma unroll
      for (int mi = 0; mi < 2; ++mi)
        av[q][mi] = *(const half8*)(BT + o * 128 + ((unsigned)(mi * 64 + kg * 16) ^ sw));
    }
#pragma unroll
    for (int ni = 0; ni < 4; ++ni) {
      int n = ni * 16 + ln;
      unsigned sw = (unsigned)((n & 7) << 4);
#pragma unroll
      for (int mi = 0; mi < 2; ++mi)
        bv[ni][mi] = *(const half8*)(AT + n * 128 + ((unsigned)(mi * 64 + kg * 16) ^ sw));
    }
#pragma unroll
    for (int mi = 0; mi < 2; ++mi)
#pragma unroll
      for (int q = 0; q < 4; ++q)
#pragma unroll
        for (int ni = 0; ni < 4; ++ni)
          acc[q][ni] = __builtin_amdgcn_mfma_f32_16x16x32_f16(av[q][mi], bv[ni][mi], acc[q][ni], 0, 0, 0);
    __syncthreads();
    if (kt < 3) { issueA(kt + 1); issueB1(kt + 1); __syncthreads(); }
  }

  // ---- b1 + LN1 partials (BT dead; stats live in its tail) ----
  {
    f32x4 b1v[4];
#pragma unroll
    for (int q = 0; q < 4; ++q)
      b1v[q] = *(const f32x4*)(b1 + (w * 4 + q) * 16 + kg * 4);
#pragma unroll
    for (int ni = 0; ni < 4; ++ni) {
      float s = 0.f, qq = 0.f;
#pragma unroll
      for (int q = 0; q < 4; ++q)
#pragma unroll
        for (int r = 0; r < 4; ++r) {
          float v = acc[q][ni][r] + b1v[q][r];
          acc[q][ni][r] = v;
          s += v; qq += v * v;
        }
      s += __shfl_xor(s, 16, 64); s += __shfl_xor(s, 32, 64);
      qq += __shfl_xor(qq, 16, 64); qq += __shfl_xor(qq, 32, 64);
      if (kg == 0) { int n = ni * 16 + ln; pS[n * 5 + w] = s; pQ[n * 5 + w] = qq; }
    }
  }
  __syncthreads();
  if (t < 64) {
    float s = pS[t * 5 + 0] + pS[t * 5 + 1] + pS[t * 5 + 2] + pS[t * 5 + 3];
    float q = pQ[t * 5 + 0] + pQ[t * 5 + 1] + pQ[t * 5 + 2] + pQ[t * 5 + 3];
    float mean = s * (1.f / 256.f);
    float var = q * (1.f / 256.f) - mean * mean;
    pM[t] = mean;
    pR[t] = rsqrtf(var + 1e-5f);
  }
  __syncthreads();

  // ---- LN1 apply + ReLU -> H1 (overwrites AT + lower BT) ----
  {
    f32x4 g1v[4], e1v[4];
#pragma unroll
    for (int q = 0; q < 4; ++q) {
      g1v[q] = *(const f32x4*)(g1 + (w * 4 + q) * 16 + kg * 4);
      e1v[q] = *(const f32x4*)(be1 + (w * 4 + q) * 16 + kg * 4);
    }
#pragma unroll
    for (int ni = 0; ni < 4; ++ni) {
      int n = ni * 16 + ln;
      float mean = pM[n], rstd = pR[n];
      unsigned sw = (unsigned)((n & 7) << 4);
#pragma unroll
      for (int q = 0; q < 4; ++q) {
        half4 hv;
#pragma unroll
        for (int r = 0; r < 4; ++r) {
          float y = (acc[q][ni][r] - mean) * rstd * g1v[q][r] + e1v[q][r];
          hv[r] = (f16)fmaxf(y, 0.f);
        }
        *(half4*)(H1 + ((unsigned)(n * 512 + (w * 4 + q) * 32 + kg * 8) ^ sw)) = hv;
      }
    }
  }
  __syncthreads();  // H1 visible

  // ---- MLP2 [128 o2]x[64 n], K=256: W2 frag-major from L2 -> regs, barrier-free ----
  f32x4 acc2[2][4];
#pragma unroll
  for (int oi = 0; oi < 2; ++oi)
#pragma unroll
    for (int ni = 0; ni < 4; ++ni)
#pragma unroll
      for (int i = 0; i < 4; ++i) acc2[oi][ni][i] = 0.f;
#pragma unroll
  for (int kt = 0; kt < 4; ++kt) {
    half8 a2[2][2], bv[4][2];
#pragma unroll
    for (int oi = 0; oi < 2; ++oi)
#pragma unroll
      for (int mi = 0; mi < 2; ++mi)
        a2[oi][mi] = *(const half8*)(W2g + ((((w * 2 + oi) * 4 + kt) * 2 + mi) << 10) + (lane << 4));
#pragma unroll
    for (int ni = 0; ni < 4; ++ni) {
      int n = ni * 16 + ln;
      unsigned sw = (unsigned)((n & 7) << 4);
#pragma unroll
      for (int mi = 0; mi < 2; ++mi)
        bv[ni][mi] = *(const half8*)(H1 + n * 512 + kt * 128 + ((unsigned)(mi * 64 + kg * 16) ^ sw));
    }
#pragma unroll
    for (int mi = 0; mi < 2; ++mi)
#pragma unroll
      for (int oi = 0; oi < 2; ++oi)
#pragma unroll
        for (int ni = 0; ni < 4; ++ni)
          acc2[oi][ni] = __builtin_amdgcn_mfma_f32_16x16x32_f16(a2[oi][mi], bv[ni][mi], acc2[oi][ni], 0, 0, 0);
  }

  // ---- LN2 + ReLU + w3 dot + sigmoid -> fi ----
  {
    f32x4 b2v[2], g2v[2], e2v[2], w3v[2];
#pragma unroll
    for (int oi = 0; oi < 2; ++oi) {
      b2v[oi] = *(const f32x4*)(b2 + (w * 2 + oi) * 16 + kg * 4);
      g2v[oi] = *(const f32x4*)(g2 + (w * 2 + oi) * 16 + kg * 4);
      e2v[oi] = *(const f32x4*)(be2 + (w * 2 + oi) * 16 + kg * 4);
      w3v[oi] = *(const f32x4*)(w3 + (w * 2 + oi) * 16 + kg * 4);
    }
    __syncthreads();  // prior pS/pQ reads (LN1 stats) done
#pragma unroll
    for (int ni = 0; ni < 4; ++ni) {
      float s = 0.f, q = 0.f;
#pragma unroll
      for (int oi = 0; oi < 2; ++oi)
#pragma unroll
        for (int r = 0; r < 4; ++r) {
          float v = acc2[oi][ni][r] + b2v[oi][r];
          acc2[oi][ni][r] = v;
          s += v; q += v * v;
        }
      s += __shfl_xor(s, 16, 64); s += __shfl_xor(s, 32, 64);
      q += __shfl_xor(q, 16, 64); q += __shfl_xor(q, 32, 64);
      if (kg == 0) { int n = ni * 16 + ln; pS[n * 5 + w] = s; pQ[n * 5 + w] = q; }
    }
    __syncthreads();
    if (t < 64) {
      float s = pS[t * 5 + 0] + pS[t * 5 + 1] + pS[t * 5 + 2] + pS[t * 5 + 3];
      float q = pQ[t * 5 + 0] + pQ[t * 5 + 1] + pQ[t * 5 + 2] + pQ[t * 5 + 3];
      float mean = s * (1.f / 128.f);
      float var = q * (1.f / 128.f) - mean * mean;
      pM[t] = mean;
      pR[t] = rsqrtf(var + 1e-5f);
    }
    __syncthreads();
#pragma unroll
    for (int ni = 0; ni < 4; ++ni) {
      int n = ni * 16 + ln;
      float mean = pM[n], rstd = pR[n];
      float a3 = 0.f;
#pragma unroll
      for (int oi = 0; oi < 2; ++oi)
#pragma unroll
        for (int r = 0; r < 4; ++r) {
          float y = (acc2[oi][ni][r] - mean) * rstd * g2v[oi][r] + e2v[oi][r];
          a3 += fmaxf(y, 0.f) * w3v[oi][r];
        }
      a3 += __shfl_xor(a3, 16, 64);
      a3 += __shfl_xor(a3, 32, 64);
      if (kg == 0) pS[n * 5 + w] = a3;
    }
    __syncthreads();
    if (t < 64) {
      float z = pS[t * 5 + 0] + pS[t * 5 + 1] + pS[t * 5 + 2] + pS[t * 5 + 3] + b3[0];
      fi[(size_t)b * 16384 + n0 + t] = sigm(z);
    }
  }
}

// ---------------- G4: ktop + pick sim candidate + min/max reductions ----------------
__global__ void __launch_bounds__(256) k_g4(
    const float* __restrict__ cand, const float* __restrict__ fi,
    const float* __restrict__ varpart, const float* __restrict__ kw,
    float* __restrict__ sim, unsigned* __restrict__ simMM, unsigned* __restrict__ fiMM) {
  __shared__ float red[4][4];
  __shared__ int kS;
  int b = blockIdx.x >> 6;
  if (threadIdx.x < 64) {
    float s = 0.f;
#pragma unroll
    for (int i = 0; i < 4; ++i) s += varpart[b * 256 + threadIdx.x + i * 64];
#pragma unroll
    for (int m = 1; m < 64; m <<= 1) s += __shfl_xor(s, m, 64);
    if (threadIdx.x == 0) {
      float var = s * (1.f / 16384.f);
      float kws = sigm(kw[0]);
      float ratio = fminf(fmaxf(kws * (1.f + var * 0.5f), 0.25f), 0.6f);
      int kb = (int)floorf(32.f * ratio);
      if (kb < 1) kb = 1;
      int kt = kb < 16 ? kb : 16;
      if (kt < 8) kt = 8;
      kS = kt;
    }
  }
  __syncthreads();
  int k = kS;
  int n = (blockIdx.x & 63) * 256 + threadIdx.x;
  size_t idx = (size_t)b * 16384 + n;
  float sv = cand[(size_t)(k - 8) * 262144 + idx];
  sim[idx] = sv;
  float fv = fi[idx];
  float sn = sv, sx = sv, fn = fv, fx = fv;
#pragma unroll
  for (int m = 1; m < 64; m <<= 1) {
    sn = fminf(sn, __shfl_xor(sn, m, 64));
    sx = fmaxf(sx, __shfl_xor(sx, m, 64));
    fn = fminf(fn, __shfl_xor(fn, m, 64));
    fx = fmaxf(fx, __shfl_xor(fx, m, 64));
  }
  int wv = threadIdx.x >> 6;
  if ((threadIdx.x & 63) == 0) { red[0][wv] = sn; red[1][wv] = sx; red[2][wv] = fn; red[3][wv] = fx; }
  __syncthreads();
  if (threadIdx.x == 0) {
    float a = red[0][0], c = red[1][0], d = red[2][0], e = red[3][0];
#pragma unroll
    for (int i = 1; i < 4; ++i) {
      a = fminf(a, red[0][i]); c = fmaxf(c, red[1][i]);
      d = fminf(d, red[2][i]); e = fmaxf(e, red[3][i]);
    }
    atomicMin(&simMM[b * 2 + 0], fmap(a));
    atomicMax(&simMM[b * 2 + 1], fmap(c));
    atomicMin(&fiMM[b * 2 + 0], fmap(d));
    atomicMax(&fiMM[b * 2 + 1], fmap(e));
  }
}

// ---------------- G5: normalize, combine, transpose-write ----------------
__global__ void __launch_bounds__(256) k_g5(
    const float* __restrict__ sim, const float* __restrict__ fi,
    const unsigned* __restrict__ simMM, const unsigned* __restrict__ fiMM,
    const float* __restrict__ ac, const float* __restrict__ af,
    float* __restrict__ out) {
  __shared__ float ls[256][17], lf[256][17];
  __shared__ float sMin[16], sInv[16], fMin[16], fInv[16];
  int t = threadIdx.x;
  int n0 = blockIdx.x * 256;
  if (t < 16) {
    float lo = funmap(simMM[t * 2]), hi = funmap(simMM[t * 2 + 1]);
    float r = hi - lo;
    sMin[t] = lo; sInv[t] = (r > 0.f) ? 1.f / r : 0.f;
    lo = funmap(fiMM[t * 2]); hi = funmap(fiMM[t * 2 + 1]);
    r = hi - lo;
    fMin[t] = lo; fInv[t] = (r > 0.f) ? 1.f / r : 0.f;
  }
#pragma unroll
  for (int i = 0; i < 16; ++i) {
    ls[t][i] = sim[(size_t)i * 16384 + n0 + t];
    lf[t][i] = fi[(size_t)i * 16384 + n0 + t];
  }
  __syncthreads();
  float alpha = 0.5f * (sigm(ac[0]) + sigm(af[0]));
  float o[16];
#pragma unroll
  for (int b = 0; b < 16; ++b) {
    float s = (ls[t][b] - sMin[b]) * sInv[b];
    float f = (lf[t][b] - fMin[b]) * fInv[b];
    o[b] = alpha * s + (1.f - alpha) * f;
  }
  float* op = out + (size_t)(n0 + t) * 16;
#pragma unroll
  for (int i = 0; i < 4; ++i) {
    f32x4 v;
    v[0] = o[i * 4]; v[1] = o[i * 4 + 1]; v[2] = o[i * 4 + 2]; v[3] = o[i * 4 + 3];
    *(f32x4*)(op + i * 4) = v;
  }
}

// ---------------- launcher ----------------
extern "C" void kernel_launch(void* const* d_in, const int* in_sizes, int n_in,
                              void* d_out, int out_size, void* d_ws, size_t ws_size,
                              hipStream_t stream) {
  const float* X    = (const float*)d_in[0];
  const float* T    = (const float*)d_in[1];
  const float* vp_w = (const float*)d_in[2];
  const float* vp_b = (const float*)d_in[3];
  const float* tp_w = (const float*)d_in[4];
  const float* tp_b = (const float*)d_in[5];
  const float* ipw  = (const float*)d_in[6];
  const float* ipb  = (const float*)d_in[7];
  const float* w1   = (const float*)d_in[8];
  const float* b1   = (const float*)d_in[9];
  const float* g1   = (const float*)d_in[10];
  const float* be1  = (const float*)d_in[11];
  const float* w2   = (const float*)d_in[12];
  const float* b2   = (const float*)d_in[13];
  const float* g2   = (const float*)d_in[14];
  const float* be2  = (const float*)d_in[15];
  const float* w3   = (const float*)d_in[16];
  const float* b3   = (const float*)d_in[17];
  const float* kw   = (const float*)d_in[18];
  const float* ac   = (const float*)d_in[19];
  const float* af   = (const float*)d_in[20];
  char* ws = (char*)d_ws;
  float* Wqv = (float*)(ws + WQV_OFF);
  float* Wkt = (float*)(ws + WKT_OFF);
  float* kp = (float*)(ws + KP_OFF);
  char* W2sg = ws + W2S_OFF;
  float* sbias = (float*)(ws + SBIAS_OFF);
  float* bqv = (float*)(ws + BQV_OFF);
  float* bkt = (float*)(ws + BKT_OFF);
  char* W1g = ws + W1H_OFF;
  char* W2g = ws + W2H_OFF;
  float* varpart = (float*)(ws + VARP_OFF);
  unsigned* simMM = (unsigned*)(ws + SMM_OFF);
  unsigned* fiMM = (unsigned*)(ws + FMM_OFF);
  float* cand = (float*)(ws + CAND_OFF);
  float* fi = (float*)(ws + FI_OFF);
  float* sim = (float*)(ws + SIM_OFF);
  float* out = (float*)d_out;

  k_p1<<<dim3(16, 16, 3), dim3(16, 16), 0, stream>>>(ipw, ipb, vp_w, vp_b, tp_w, tp_b,
                                                     Wqv, Wkt, bqv, bkt, simMM, fiMM);
  k_conv<<<384, 256, 0, stream>>>(w1, w2, W1g, W2g);
  k_p2<<<dim3(16, 32), dim3(16, 16), 0, stream>>>(T, Wkt, bkt, kp);
  k_p3<<<dim3(16, 16, 16), dim3(16, 16), 0, stream>>>(kp, Wqv, bqv, W2sg, sbias);
  k_main<<<dim3(512, 16), 256, 0, stream>>>(X, W2sg, sbias, W1g, W2g,
                                            b1, g1, be1, b2, g2, be2, w3, b3,
                                            cand, varpart, fi);
  k_g4<<<1024, 256, 0, stream>>>(cand, fi, varpart, kw, sim, simMM, fiMM);
  k_g5<<<64, 256, 0, stream>>>(sim, fi, simMM, fiMM, ac, af, out);
}

// Round 16
// 250.276 us; speedup vs baseline: 1.0726x; 1.0726x over previous
//
#include <hip/hip_runtime.h>
#include <hip/hip_bf16.h>

typedef _Float16 f16;
typedef _Float16 half8 __attribute__((ext_vector_type(8)));
typedef _Float16 half4 __attribute__((ext_vector_type(4)));
typedef float f32x4 __attribute__((ext_vector_type(4)));

typedef const __attribute__((address_space(1))) void gvoid;
typedef __attribute__((address_space(3))) void lvoid;
#define GLOAD16(src, dst) __builtin_amdgcn_global_load_lds((gvoid*)(src), (lvoid*)(dst), 16, 0, 0)

// ---------------- workspace layout (bytes) ----------------
#define WQV_OFF   0u          // f32 [256][256]  Wq*Vp
#define WKT_OFF   262144u     // f32 [256][256]  Wk*Tp
#define KP_OFF    524288u     // f32 [512][256]  fused k-projection (l*16+b rows)
#define W2S_OFF   1048576u    // row-image W2s: [16 b][4 kc][256 j][128B] (swizzle baked)
#define SBIAS_OFF 3145728u    // f32 [16][256]
#define BQV_OFF   3162112u    // f32 [256]
#define BKT_OFF   3163136u    // f32 [256]
#define W1H_OFF   3164160u    // row-image W1: [4 kc][256 o][128B]
#define W2H_OFF   3295232u    // frag-major W2: [8 ot][4 kc][2 mi][64 lane][16B] (64 KB)
#define VARP_OFF  3360768u    // f32 [16][256]
#define SMM_OFF   3377280u    // u32 [16][2]
#define FMM_OFF   3377408u    // u32 [16][2]
#define CAND_OFF  3377664u    // f32 [9][16][16384]  plane-major candidates
#define FI_OFF    12814848u   // f32 [16][16384]
#define SIM_OFF   13863424u   // f32 [16][16384]

__device__ __forceinline__ float sigm(float x) { return 1.f / (1.f + __expf(-x)); }
__device__ __forceinline__ unsigned fmap(float f) {
  unsigned u = __float_as_uint(f);
  return (u & 0x80000000u) ? ~u : (u | 0x80000000u);
}
__device__ __forceinline__ float funmap(unsigned u) {
  unsigned b = (u & 0x80000000u) ? (u & 0x7FFFFFFFu) : ~u;
  return __uint_as_float(b);
}
// frag-major byte offset for element (row o, col c) of a [O][256] f16 matrix
__device__ __forceinline__ unsigned fragoff(int o, int c) {
  int ot = o >> 4, ln = o & 15;
  int kc = c >> 6, mi = (c >> 5) & 1, kg = (c >> 3) & 3, h8 = c & 7;
  return (unsigned)((((ot * 4 + kc) * 2 + mi) << 10) + ((kg * 16 + ln) << 4) + h8 * 2);
}

// ---------------- P1: Wqv = Wq*Vp, Wkt = Wk*Tp, fused biases (+minmax init) --------
__global__ void k_p1(const float* __restrict__ ipw, const float* __restrict__ ipb,
                     const float* __restrict__ vp_w, const float* __restrict__ vp_b,
                     const float* __restrict__ tp_w, const float* __restrict__ tp_b,
                     float* __restrict__ Wqv, float* __restrict__ Wkt,
                     float* __restrict__ bqv, float* __restrict__ bkt,
                     unsigned* __restrict__ simMM, unsigned* __restrict__ fiMM) {
  int tx = threadIdx.x, ty = threadIdx.y;
  int bz = blockIdx.z;
  if (bz == 2) {
    if (blockIdx.x || blockIdx.y) return;
    if (ty == 0 && tx < 16) {
      simMM[tx * 2] = 0xFFFFFFFFu; simMM[tx * 2 + 1] = 0u;
      fiMM[tx * 2] = 0xFFFFFFFFu;  fiMM[tx * 2 + 1] = 0u;
    }
    int j = ty * 16 + tx;
    float s1 = 0.f, s2 = 0.f;
    for (int k = 0; k < 256; ++k) {
      s1 += ipw[j * 256 + k] * vp_b[k];
      s2 += ipw[65536 + j * 256 + k] * tp_b[k];
    }
    bqv[j] = s1 + ipb[j];
    bkt[j] = s2 + ipb[256 + j];
    return;
  }
  const float* A = ipw + (bz ? 65536 : 0);
  const float* B = bz ? tp_w : vp_w;
  float* O = bz ? Wkt : Wqv;
  __shared__ float As[16][16], Bs[16][17];
  int row = blockIdx.y * 16 + ty, col = blockIdx.x * 16 + tx;
  float s = 0.f;
  for (int tt = 0; tt < 16; ++tt) {
    As[ty][tx] = A[row * 256 + tt * 16 + tx];
    Bs[ty][tx] = B[(tt * 16 + ty) * 256 + col];
    __syncthreads();
#pragma unroll
    for (int k = 0; k < 16; ++k) s += As[ty][k] * Bs[k][tx];
    __syncthreads();
  }
  O[row * 256 + col] = s;
}

// ---------------- convert: W1 -> row-image, W2 -> frag-major ----------------
__global__ void k_conv(const float* __restrict__ w1, const float* __restrict__ w2,
                       char* __restrict__ W1g, char* __restrict__ W2g) {
  int i = blockIdx.x * 256 + threadIdx.x;
  if (i < 65536) {
    int o = i >> 8, c = i & 255;
    *(f16*)(W1g + (c >> 6) * 32768 + o * 128 + (((c & 63) << 1) ^ ((o & 7) << 4))) = (f16)w1[i];
  } else if (i < 98304) {
    int i2 = i - 65536;
    int o = i2 >> 8, c = i2 & 255;
    *(f16*)(W2g + fragoff(o, c)) = (f16)w2[i2];
  }
}

// ---------------- P2: kp[lb][i] = T[lb]·Wkt[i] + bkt[i] ----------------
__global__ void k_p2(const float* __restrict__ T, const float* __restrict__ Wkt,
                     const float* __restrict__ bkt, float* __restrict__ kp) {
  __shared__ float As[16][16], Ws[16][17];
  int tx = threadIdx.x, ty = threadIdx.y;
  int lb = blockIdx.y * 16 + ty;
  int i = blockIdx.x * 16 + tx;
  float s = 0.f;
  for (int tt = 0; tt < 16; ++tt) {
    As[ty][tx] = T[(size_t)lb * 256 + tt * 16 + tx];
    Ws[ty][tx] = Wkt[(size_t)(blockIdx.x * 16 + ty) * 256 + tt * 16 + tx];
    __syncthreads();
#pragma unroll
    for (int k = 0; k < 16; ++k) s += As[ty][k] * Ws[tx][k];
    __syncthreads();
  }
  kp[(size_t)lb * 256 + i] = s + bkt[i];
}

// ---------------- P3: W2s (pre-swizzled row-image) + sbias ----------------
__global__ void k_p3(const float* __restrict__ kp, const float* __restrict__ Wqv,
                     const float* __restrict__ bqv, char* __restrict__ W2sg,
                     float* __restrict__ sbias) {
  const float SC = 0.17677669529663687f; // 1/sqrt(32)
  int b = blockIdx.z, jt = blockIdx.y, ct = blockIdx.x;
  int ty = threadIdx.y, tx = threadIdx.x;
  int j2 = jt * 16 + ty, c = ct * 16 + tx;
  int h = j2 >> 5, l = j2 & 31;
  const float* kr = kp + (size_t)(l * 16 + b) * 256 + h * 32;
  const float* wq = Wqv + (size_t)h * 32 * 256 + c;
  float s = 0.f;
#pragma unroll
  for (int d = 0; d < 32; ++d) s += kr[d] * wq[(size_t)d * 256];
  *(f16*)(W2sg + (size_t)b * 131072 + (c >> 6) * 32768 + j2 * 128 +
          (((c & 63) << 1) ^ ((j2 & 7) << 4))) = (f16)(s * SC);
  if (ct == 0 && tx == 0) {
    float sb = 0.f;
#pragma unroll
    for (int d = 0; d < 32; ++d) sb += kr[d] * bqv[h * 32 + d];
    sbias[b * 256 + j2] = sb * SC;
  }
}

// ============ k_main: single-X-read fusion. X staged ONCE -> scores -> MLP1 -> MLP2 ============
// LDS: XT [64n][256K] f16 @0 (32K, -> H1 after MLP1) ; WB @32K (32K, W chunk / slices) ;
// stats @64K (3K). 68.6 KB -> 2 blocks/CU.
__global__ void __launch_bounds__(256, 2) k_main(
    const float* __restrict__ X, const char* __restrict__ W2sg,
    const float* __restrict__ sbias,
    const char* __restrict__ W1g, const char* __restrict__ W2g,
    const float* __restrict__ b1, const float* __restrict__ g1, const float* __restrict__ be1,
    const float* __restrict__ b2, const float* __restrict__ g2, const float* __restrict__ be2,
    const float* __restrict__ w3, const float* __restrict__ b3,
    float* __restrict__ cand, float* __restrict__ varpart, float* __restrict__ fi) {
  __shared__ __align__(16) char smem[68608];
  const int b = blockIdx.y;
  const int bx = blockIdx.x;
  const int n0 = bx * 64;
  const int t = threadIdx.x;
  const int w = t >> 6;
  const int lane = t & 63;
  const int ln = lane & 15, kg = lane >> 4;
  char* XT = smem;            // X tile (later H1)
  char* WB = smem + 32768;    // weight chunk / softmax slices
  float* pS = (float*)(smem + 65536);   // [64][5]
  float* pQ = (float*)(smem + 66816);   // [64][5]
  float* pM = (float*)(smem + 68096);   // [64]
  float* pR = (float*)(smem + 68352);   // [64]

  // ---- stage full X tile f16[64 n][256 K] (swizzled granules) ----
  {
    int row = t >> 2, cq = t & 3;
    const float* Xr = X + ((size_t)(n0 + row) * 16 + b) * 256;
    unsigned sw = (unsigned)((row & 7) << 4);
#pragma unroll
    for (int kt = 0; kt < 4; ++kt) {
      f32x4 a0 = *(const f32x4*)(Xr + kt * 64 + cq * 16);
      f32x4 a1 = *(const f32x4*)(Xr + kt * 64 + cq * 16 + 4);
      f32x4 a2 = *(const f32x4*)(Xr + kt * 64 + cq * 16 + 8);
      f32x4 a3 = *(const f32x4*)(Xr + kt * 64 + cq * 16 + 12);
      half8 h0, h1;
#pragma unroll
      for (int i = 0; i < 4; ++i) {
        h0[i] = (f16)a0[i]; h0[4 + i] = (f16)a1[i];
        h1[i] = (f16)a2[i]; h1[4 + i] = (f16)a3[i];
      }
      unsigned base = (unsigned)(row * 512 + kt * 128 + cq * 32);
      *(half8*)(XT + ((base) ^ sw)) = h0;
      *(half8*)(XT + ((base + 16) ^ sw)) = h1;
    }
  }

  auto issueW = [&](const char* Wimg, int kt) {  // 32KB row-image chunk -> WB
    const char* src = Wimg + kt * 32768 + w * 8192 + (lane << 4);
    char* dst = WB + w * 8192;
#pragma unroll
    for (int i = 0; i < 8; ++i) GLOAD16(src + i * 1024, dst + i * 1024);
  };

  f32x4 acc[4][4];
  auto zeroAcc = [&]() {
#pragma unroll
    for (int q = 0; q < 4; ++q)
#pragma unroll
      for (int ni = 0; ni < 4; ++ni)
#pragma unroll
        for (int i = 0; i < 4; ++i) acc[q][ni][i] = 0.f;
  };
  // one kt chunk: av from WB (row-image), bv from XT resident
  auto gemm_kt = [&](int kt) {
    half8 av[4][2], bv[4][2];
#pragma unroll
    for (int q = 0; q < 4; ++q) {
      int o = w * 64 + q * 16 + ln;
      unsigned sw = (unsigned)((o & 7) << 4);
#pragma unroll
      for (int mi = 0; mi < 2; ++mi)
        av[q][mi] = *(const half8*)(WB + o * 128 + ((unsigned)(mi * 64 + kg * 16) ^ sw));
    }
#pragma unroll
    for (int ni = 0; ni < 4; ++ni) {
      int n = ni * 16 + ln;
      unsigned sw = (unsigned)((n & 7) << 4);
#pragma unroll
      for (int mi = 0; mi < 2; ++mi)
        bv[ni][mi] = *(const half8*)(XT + n * 512 + kt * 128 + ((unsigned)(mi * 64 + kg * 16) ^ sw));
    }
#pragma unroll
    for (int mi = 0; mi < 2; ++mi)
#pragma unroll
      for (int q = 0; q < 4; ++q)
#pragma unroll
        for (int ni = 0; ni < 4; ++ni)
          acc[q][ni] = __builtin_amdgcn_mfma_f32_16x16x32_f16(av[q][mi], bv[ni][mi], acc[q][ni], 0, 0, 0);
  };

  // ================= pass A: scores GEMM =================
  zeroAcc();
  issueW(W2sg + (size_t)b * 131072, 0);
  __syncthreads();  // X staged + W0 ready
#pragma unroll
  for (int kt = 0; kt < 4; ++kt) {
    gemm_kt(kt);
    __syncthreads();  // WB reads done
    if (kt < 3) { issueW(W2sg + (size_t)b * 131072, kt + 1); __syncthreads(); }
  }

  // ---- per-head softmax (wave w: heads 2w, 2w+1), slices into dead WB ----
  {
    f32x4 sb[4];
#pragma unroll
    for (int q = 0; q < 4; ++q)
      sb[q] = *(const f32x4*)(sbias + b * 256 + (w * 4 + q) * 16 + kg * 4);
    float vm[4][2][4];
#pragma unroll
    for (int ni = 0; ni < 4; ++ni)
#pragma unroll
      for (int qq = 0; qq < 2; ++qq)
#pragma unroll
        for (int r = 0; r < 4; ++r) vm[ni][qq][r] = 0.f;
#pragma unroll
    for (int hh = 0; hh < 2; ++hh)
#pragma unroll
      for (int ni = 0; ni < 4; ++ni) {
        float x[2][4];
        float mx = -1e30f;
#pragma unroll
        for (int qq = 0; qq < 2; ++qq)
#pragma unroll
          for (int r = 0; r < 4; ++r) {
            x[qq][r] = acc[hh * 2 + qq][ni][r] + sb[hh * 2 + qq][r];
            mx = fmaxf(mx, x[qq][r]);
          }
        mx = fmaxf(mx, __shfl_xor(mx, 16, 64));
        mx = fmaxf(mx, __shfl_xor(mx, 32, 64));
        float S = 0.f;
#pragma unroll
        for (int qq = 0; qq < 2; ++qq)
#pragma unroll
          for (int r = 0; r < 4; ++r) { x[qq][r] = __expf(x[qq][r] - mx); S += x[qq][r]; }
        S += __shfl_xor(S, 16, 64);
        S += __shfl_xor(S, 32, 64);
        float inv = 0.125f / S;
#pragma unroll
        for (int qq = 0; qq < 2; ++qq)
#pragma unroll
          for (int r = 0; r < 4; ++r) vm[ni][qq][r] += x[qq][r] * inv;
      }
    float* slice = (float*)WB + w * 2048;  // [32 l][64 n]
#pragma unroll
    for (int ni = 0; ni < 4; ++ni)
#pragma unroll
      for (int qq = 0; qq < 2; ++qq)
#pragma unroll
        for (int r = 0; r < 4; ++r)
          slice[(qq * 16 + kg * 4 + r) * 64 + ni * 16 + ln] = vm[ni][qq][r];
  }
  __syncthreads();

  // ---- wave 0: merge slices, variance, sort, candidates ----
  if (w == 0) {
    const float* sl = (const float*)WB;
    float v[32];
#pragma unroll
    for (int l = 0; l < 32; ++l)
      v[l] = sl[l * 64 + lane] + sl[2048 + l * 64 + lane] +
             sl[4096 + l * 64 + lane] + sl[6144 + l * 64 + lane];
    float s2 = 0.f;
#pragma unroll
    for (int l = 0; l < 32; ++l) s2 += v[l] * v[l];
    float vr = (s2 - (1.f / 32.f)) * (1.f / 31.f);
#pragma unroll
    for (int m = 1; m < 64; m <<= 1) vr += __shfl_xor(vr, m, 64);
    if (lane == 0) varpart[b * 256 + bx] = vr;
#pragma unroll
    for (int k = 2; k <= 32; k <<= 1) {
#pragma unroll
      for (int j = k >> 1; j > 0; j >>= 1) {
#pragma unroll
        for (int i = 0; i < 32; ++i) {
          int l = i ^ j;
          if (l > i) {
            float a = v[i], c = v[l];
            float hi = fmaxf(a, c), lo = fminf(a, c);
            bool up = ((i & k) == 0);
            v[i] = up ? hi : lo;
            v[l] = up ? lo : hi;
          }
        }
      }
    }
    float m0 = v[0], se = 0.f, te = 0.f;
    float cn[9];
#pragma unroll
    for (int i = 0; i < 16; ++i) {
      float e = __expf(v[i] - m0);
      se += e; te += v[i] * e;
      if (i >= 7) cn[i - 7] = te / se;
    }
#pragma unroll
    for (int i = 0; i < 9; ++i)
      cand[(size_t)i * 262144 + (size_t)b * 16384 + n0 + lane] = cn[i];
  }
  __syncthreads();  // slice reads done -> WB reusable

  // ================= pass B: MLP1 GEMM (X still resident) =================
  zeroAcc();
  issueW(W1g, 0);
  __syncthreads();
#pragma unroll
  for (int kt = 0; kt < 4; ++kt) {
    gemm_kt(kt);
    __syncthreads();
    if (kt < 3) { issueW(W1g, kt + 1); __syncthreads(); }
  }

  // ---- b1 + LN1 partials ----
  {
    f32x4 b1v[4];
#pragma unroll
    for (int q = 0; q < 4; ++q)
      b1v[q] = *(const f32x4*)(b1 + (w * 4 + q) * 16 + kg * 4);
#pragma unroll
    for (int ni = 0; ni < 4; ++ni) {
      float s = 0.f, qq = 0.f;
#pragma unroll
      for (int q = 0; q < 4; ++q)
#pragma unroll
        for (int r = 0; r < 4; ++r) {
          float v = acc[q][ni][r] + b1v[q][r];
          acc[q][ni][r] = v;
          s += v; qq += v * v;
        }
      s += __shfl_xor(s, 16, 64); s += __shfl_xor(s, 32, 64);
      qq += __shfl_xor(qq, 16, 64); qq += __shfl_xor(qq, 32, 64);
      if (kg == 0) { int n = ni * 16 + ln; pS[n * 5 + w] = s; pQ[n * 5 + w] = qq; }
    }
  }
  __syncthreads();
  if (t < 64) {
    float s = pS[t * 5 + 0] + pS[t * 5 + 1] + pS[t * 5 + 2] + pS[t * 5 + 3];
    float q = pQ[t * 5 + 0] + pQ[t * 5 + 1] + pQ[t * 5 + 2] + pQ[t * 5 + 3];
    float mean = s * (1.f / 256.f);
    float var = q * (1.f / 256.f) - mean * mean;
    pM[t] = mean;
    pR[t] = rsqrtf(var + 1e-5f);
  }
  __syncthreads();

  // ---- LN1 apply + ReLU -> H1 (overwrites XT; X dead after pass B) ----
  {
    f32x4 g1v[4], e1v[4];
#pragma unroll
    for (int q = 0; q < 4; ++q) {
      g1v[q] = *(const f32x4*)(g1 + (w * 4 + q) * 16 + kg * 4);
      e1v[q] = *(const f32x4*)(be1 + (w * 4 + q) * 16 + kg * 4);
    }
#pragma unroll
    for (int ni = 0; ni < 4; ++ni) {
      int n = ni * 16 + ln;
      float mean = pM[n], rstd = pR[n];
      unsigned sw = (unsigned)((n & 7) << 4);
#pragma unroll
      for (int q = 0; q < 4; ++q) {
        half4 hv;
#pragma unroll
        for (int r = 0; r < 4; ++r) {
          float y = (acc[q][ni][r] - mean) * rstd * g1v[q][r] + e1v[q][r];
          hv[r] = (f16)fmaxf(y, 0.f);
        }
        *(half4*)(XT + ((unsigned)(n * 512 + (w * 4 + q) * 32 + kg * 8) ^ sw)) = hv;
      }
    }
  }
  __syncthreads();  // H1 visible

  // ================= pass C: MLP2 (W2 frag-major from L2, barrier-free) =================
  f32x4 acc2[2][4];
#pragma unroll
  for (int oi = 0; oi < 2; ++oi)
#pragma unroll
    for (int ni = 0; ni < 4; ++ni)
#pragma unroll
      for (int i = 0; i < 4; ++i) acc2[oi][ni][i] = 0.f;
#pragma unroll
  for (int kt = 0; kt < 4; ++kt) {
    half8 a2[2][2], bv[4][2];
#pragma unroll
    for (int oi = 0; oi < 2; ++oi)
#pragma unroll
      for (int mi = 0; mi < 2; ++mi)
        a2[oi][mi] = *(const half8*)(W2g + ((((w * 2 + oi) * 4 + kt) * 2 + mi) << 10) + (lane << 4));
#pragma unroll
    for (int ni = 0; ni < 4; ++ni) {
      int n = ni * 16 + ln;
      unsigned sw = (unsigned)((n & 7) << 4);
#pragma unroll
      for (int mi = 0; mi < 2; ++mi)
        bv[ni][mi] = *(const half8*)(XT + n * 512 + kt * 128 + ((unsigned)(mi * 64 + kg * 16) ^ sw));
    }
#pragma unroll
    for (int mi = 0; mi < 2; ++mi)
#pragma unroll
      for (int oi = 0; oi < 2; ++oi)
#pragma unroll
        for (int ni = 0; ni < 4; ++ni)
          acc2[oi][ni] = __builtin_amdgcn_mfma_f32_16x16x32_f16(a2[oi][mi], bv[ni][mi], acc2[oi][ni], 0, 0, 0);
  }

  // ---- LN2 + ReLU + w3 dot + sigmoid -> fi ----
  {
    f32x4 b2v[2], g2v[2], e2v[2], w3v[2];
#pragma unroll
    for (int oi = 0; oi < 2; ++oi) {
      b2v[oi] = *(const f32x4*)(b2 + (w * 2 + oi) * 16 + kg * 4);
      g2v[oi] = *(const f32x4*)(g2 + (w * 2 + oi) * 16 + kg * 4);
      e2v[oi] = *(const f32x4*)(be2 + (w * 2 + oi) * 16 + kg * 4);
      w3v[oi] = *(const f32x4*)(w3 + (w * 2 + oi) * 16 + kg * 4);
    }
    __syncthreads();  // LN1 stats reads done -> reuse pS/pQ
#pragma unroll
    for (int ni = 0; ni < 4; ++ni) {
      float s = 0.f, q = 0.f;
#pragma unroll
      for (int oi = 0; oi < 2; ++oi)
#pragma unroll
        for (int r = 0; r < 4; ++r) {
          float v = acc2[oi][ni][r] + b2v[oi][r];
          acc2[oi][ni][r] = v;
          s += v; q += v * v;
        }
      s += __shfl_xor(s, 16, 64); s += __shfl_xor(s, 32, 64);
      q += __shfl_xor(q, 16, 64); q += __shfl_xor(q, 32, 64);
      if (kg == 0) { int n = ni * 16 + ln; pS[n * 5 + w] = s; pQ[n * 5 + w] = q; }
    }
    __syncthreads();
    if (t < 64) {
      float s = pS[t * 5 + 0] + pS[t * 5 + 1] + pS[t * 5 + 2] + pS[t * 5 + 3];
      float q = pQ[t * 5 + 0] + pQ[t * 5 + 1] + pQ[t * 5 + 2] + pQ[t * 5 + 3];
      float mean = s * (1.f / 128.f);
      float var = q * (1.f / 128.f) - mean * mean;
      pM[t] = mean;
      pR[t] = rsqrtf(var + 1e-5f);
    }
    __syncthreads();
#pragma unroll
    for (int ni = 0; ni < 4; ++ni) {
      int n = ni * 16 + ln;
      float mean = pM[n], rstd = pR[n];
      float a3 = 0.f;
#pragma unroll
      for (int oi = 0; oi < 2; ++oi)
#pragma unroll
        for (int r = 0; r < 4; ++r) {
          float y = (acc2[oi][ni][r] - mean) * rstd * g2v[oi][r] + e2v[oi][r];
          a3 += fmaxf(y, 0.f) * w3v[oi][r];
        }
      a3 += __shfl_xor(a3, 16, 64);
      a3 += __shfl_xor(a3, 32, 64);
      if (kg == 0) pS[n * 5 + w] = a3;
    }
    __syncthreads();
    if (t < 64) {
      float z = pS[t * 5 + 0] + pS[t * 5 + 1] + pS[t * 5 + 2] + pS[t * 5 + 3] + b3[0];
      fi[(size_t)b * 16384 + n0 + t] = sigm(z);
    }
  }
}

// ---------------- G4: ktop + pick sim candidate + min/max reductions ----------------
__global__ void __launch_bounds__(256) k_g4(
    const float* __restrict__ cand, const float* __restrict__ fi,
    const float* __restrict__ varpart, const float* __restrict__ kw,
    float* __restrict__ sim, unsigned* __restrict__ simMM, unsigned* __restrict__ fiMM) {
  __shared__ float red[4][4];
  __shared__ int kS;
  int b = blockIdx.x >> 6;
  if (threadIdx.x < 64) {
    float s = 0.f;
#pragma unroll
    for (int i = 0; i < 4; ++i) s += varpart[b * 256 + threadIdx.x + i * 64];
#pragma unroll
    for (int m = 1; m < 64; m <<= 1) s += __shfl_xor(s, m, 64);
    if (threadIdx.x == 0) {
      float var = s * (1.f / 16384.f);
      float kws = sigm(kw[0]);
      float ratio = fminf(fmaxf(kws * (1.f + var * 0.5f), 0.25f), 0.6f);
      int kb = (int)floorf(32.f * ratio);
      if (kb < 1) kb = 1;
      int kt = kb < 16 ? kb : 16;
      if (kt < 8) kt = 8;
      kS = kt;
    }
  }
  __syncthreads();
  int k = kS;
  int n = (blockIdx.x & 63) * 256 + threadIdx.x;
  size_t idx = (size_t)b * 16384 + n;
  float sv = cand[(size_t)(k - 8) * 262144 + idx];
  sim[idx] = sv;
  float fv = fi[idx];
  float sn = sv, sx = sv, fn = fv, fx = fv;
#pragma unroll
  for (int m = 1; m < 64; m <<= 1) {
    sn = fminf(sn, __shfl_xor(sn, m, 64));
    sx = fmaxf(sx, __shfl_xor(sx, m, 64));
    fn = fminf(fn, __shfl_xor(fn, m, 64));
    fx = fmaxf(fx, __shfl_xor(fx, m, 64));
  }
  int wv = threadIdx.x >> 6;
  if ((threadIdx.x & 63) == 0) { red[0][wv] = sn; red[1][wv] = sx; red[2][wv] = fn; red[3][wv] = fx; }
  __syncthreads();
  if (threadIdx.x == 0) {
    float a = red[0][0], c = red[1][0], d = red[2][0], e = red[3][0];
#pragma unroll
    for (int i = 1; i < 4; ++i) {
      a = fminf(a, red[0][i]); c = fmaxf(c, red[1][i]);
      d = fminf(d, red[2][i]); e = fmaxf(e, red[3][i]);
    }
    atomicMin(&simMM[b * 2 + 0], fmap(a));
    atomicMax(&simMM[b * 2 + 1], fmap(c));
    atomicMin(&fiMM[b * 2 + 0], fmap(d));
    atomicMax(&fiMM[b * 2 + 1], fmap(e));
  }
}

// ---------------- G5: normalize, combine, transpose-write ----------------
__global__ void __launch_bounds__(256) k_g5(
    const float* __restrict__ sim, const float* __restrict__ fi,
    const unsigned* __restrict__ simMM, const unsigned* __restrict__ fiMM,
    const float* __restrict__ ac, const float* __restrict__ af,
    float* __restrict__ out) {
  __shared__ float ls[256][17], lf[256][17];
  __shared__ float sMin[16], sInv[16], fMin[16], fInv[16];
  int t = threadIdx.x;
  int n0 = blockIdx.x * 256;
  if (t < 16) {
    float lo = funmap(simMM[t * 2]), hi = funmap(simMM[t * 2 + 1]);
    float r = hi - lo;
    sMin[t] = lo; sInv[t] = (r > 0.f) ? 1.f / r : 0.f;
    lo = funmap(fiMM[t * 2]); hi = funmap(fiMM[t * 2 + 1]);
    r = hi - lo;
    fMin[t] = lo; fInv[t] = (r > 0.f) ? 1.f / r : 0.f;
  }
#pragma unroll
  for (int i = 0; i < 16; ++i) {
    ls[t][i] = sim[(size_t)i * 16384 + n0 + t];
    lf[t][i] = fi[(size_t)i * 16384 + n0 + t];
  }
  __syncthreads();
  float alpha = 0.5f * (sigm(ac[0]) + sigm(af[0]));
  float o[16];
#pragma unroll
  for (int b = 0; b < 16; ++b) {
    float s = (ls[t][b] - sMin[b]) * sInv[b];
    float f = (lf[t][b] - fMin[b]) * fInv[b];
    o[b] = alpha * s + (1.f - alpha) * f;
  }
  float* op = out + (size_t)(n0 + t) * 16;
#pragma unroll
  for (int i = 0; i < 4; ++i) {
    f32x4 v;
    v[0] = o[i * 4]; v[1] = o[i * 4 + 1]; v[2] = o[i * 4 + 2]; v[3] = o[i * 4 + 3];
    *(f32x4*)(op + i * 4) = v;
  }
}

// ---------------- launcher ----------------
extern "C" void kernel_launch(void* const* d_in, const int* in_sizes, int n_in,
                              void* d_out, int out_size, void* d_ws, size_t ws_size,
                              hipStream_t stream) {
  const float* X    = (const float*)d_in[0];
  const float* T    = (const float*)d_in[1];
  const float* vp_w = (const float*)d_in[2];
  const float* vp_b = (const float*)d_in[3];
  const float* tp_w = (const float*)d_in[4];
  const float* tp_b = (const float*)d_in[5];
  const float* ipw  = (const float*)d_in[6];
  const float* ipb  = (const float*)d_in[7];
  const float* w1   = (const float*)d_in[8];
  const float* b1   = (const float*)d_in[9];
  const float* g1   = (const float*)d_in[10];
  const float* be1  = (const float*)d_in[11];
  const float* w2   = (const float*)d_in[12];
  const float* b2   = (const float*)d_in[13];
  const float* g2   = (const float*)d_in[14];
  const float* be2  = (const float*)d_in[15];
  const float* w3   = (const float*)d_in[16];
  const float* b3   = (const float*)d_in[17];
  const float* kw   = (const float*)d_in[18];
  const float* ac   = (const float*)d_in[19];
  const float* af   = (const float*)d_in[20];
  char* ws = (char*)d_ws;
  float* Wqv = (float*)(ws + WQV_OFF);
  float* Wkt = (float*)(ws + WKT_OFF);
  float* kp = (float*)(ws + KP_OFF);
  char* W2sg = ws + W2S_OFF;
  float* sbias = (float*)(ws + SBIAS_OFF);
  float* bqv = (float*)(ws + BQV_OFF);
  float* bkt = (float*)(ws + BKT_OFF);
  char* W1g = ws + W1H_OFF;
  char* W2g = ws + W2H_OFF;
  float* varpart = (float*)(ws + VARP_OFF);
  unsigned* simMM = (unsigned*)(ws + SMM_OFF);
  unsigned* fiMM = (unsigned*)(ws + FMM_OFF);
  float* cand = (float*)(ws + CAND_OFF);
  float* fi = (float*)(ws + FI_OFF);
  float* sim = (float*)(ws + SIM_OFF);
  float* out = (float*)d_out;

  k_p1<<<dim3(16, 16, 3), dim3(16, 16), 0, stream>>>(ipw, ipb, vp_w, vp_b, tp_w, tp_b,
                                                     Wqv, Wkt, bqv, bkt, simMM, fiMM);
  k_conv<<<384, 256, 0, stream>>>(w1, w2, W1g, W2g);
  k_p2<<<dim3(16, 32), dim3(16, 16), 0, stream>>>(T, Wkt, bkt, kp);
  k_p3<<<dim3(16, 16, 16), dim3(16, 16), 0, stream>>>(kp, Wqv, bqv, W2sg, sbias);
  k_main<<<dim3(256, 16), 256, 0, stream>>>(X, W2sg, sbias, W1g, W2g,
                                            b1, g1, be1, b2, g2, be2, w3, b3,
                                            cand, varpart, fi);
  k_g4<<<1024, 256, 0, stream>>>(cand, fi, varpart, kw, sim, simMM, fiMM);
  k_g5<<<64, 256, 0, stream>>>(sim, fi, simMM, fiMM, ac, af, out);
}